// Round 15
// baseline (1228.582 us; speedup 1.0000x reference)
//
#include <hip/hip_runtime.h>
#include <math.h>

// HyperbolicGraphConvolution on MI355X.
// N=100000, D=65 (col 0 identically 0 through GCN hops -> propagate 64), E=1.6M.
// r8: row-major h -> 197MB FETCH (8-XCD replication of h), 107us/spmm, high MLP.
// r11: feature-chunked h[8][N][8] (3.2MB slab/XCD L2) fixed FETCH (158MB) but
// serialized the edge walk -> MLP collapse, 189us/spmm, VALUBusy 13%.
// r12: chunked layout + MLP restored: wave = ONE row, lanes = 8 edges x 8 feats;
// coalesced 64B edge loads (8 lanes/edge HW broadcast), 8 independent gathers
// per iter into the L2-resident slab, unconditional clamped loads, unroll 4,
// 3x shfl_xor tail reduce.

__device__ __forceinline__ float waveReduceSum(float v) {
  #pragma unroll
  for (int m = 32; m > 0; m >>= 1) v += __shfl_xor(v, m, 64);
  return v;
}

__device__ __forceinline__ void ld_edge_nt(const int2* p, int& c, float& v) {
  unsigned long long u =
      __builtin_nontemporal_load((const unsigned long long*)p);
  c = (int)(u & 0xffffffffull);
  v = __int_as_float((int)(u >> 32));
}

// logmap0 -> chunk-major t[8][n][8]: t[f>>3][row][f&7]
__global__ __launch_bounds__(256) void k_logmap0(const float* __restrict__ x,
                                                 float* __restrict__ t, int n) {
  int wid = (blockIdx.x * blockDim.x + threadIdx.x) >> 6;
  int lane = threadIdx.x & 63;
  if (wid >= n) return;
  const float* row = x + (size_t)wid * 65;
  float x0 = row[0];
  float y = row[1 + lane];
  float ss = waveReduceSum(y * y);
  float nrm = fmaxf(sqrtf(ss), 1e-15f);
  float theta = fmaxf(x0, 1.0f + 1e-7f);
  float val = acoshf(theta) * (y / nrm);
  t[(size_t)(lane >> 3) * n * 8 + (size_t)wid * 8 + (lane & 7)] = val;
}

__global__ void k_hist(const int* __restrict__ rows, int* __restrict__ cnt, int e) {
  int i = blockIdx.x * blockDim.x + threadIdx.x;
  int stride = gridDim.x * blockDim.x;
  for (; i < e; i += stride) atomicAdd(&cnt[rows[i]], 1);
}

// ---- 3-phase multi-block exclusive scan over cnt[0..n) ----
__global__ __launch_bounds__(1024) void k_scan1(const int* __restrict__ cnt,
                                                int* __restrict__ off,
                                                int* __restrict__ bsum, int n) {
  __shared__ int sh[1024];
  int i = blockIdx.x * 1024 + threadIdx.x;
  int v = (i < n) ? cnt[i] : 0;
  sh[threadIdx.x] = v;
  __syncthreads();
  #pragma unroll
  for (int d = 1; d < 1024; d <<= 1) {
    int t = (threadIdx.x >= d) ? sh[threadIdx.x - d] : 0;
    __syncthreads();
    sh[threadIdx.x] += t;
    __syncthreads();
  }
  if (i < n) off[i] = sh[threadIdx.x] - v;
  if (threadIdx.x == 1023) bsum[blockIdx.x] = sh[1023];
}

__global__ __launch_bounds__(1024) void k_scan2(int* __restrict__ bsum, int nb) {
  __shared__ int sh[1024];
  int v = (threadIdx.x < nb) ? bsum[threadIdx.x] : 0;
  sh[threadIdx.x] = v;
  __syncthreads();
  #pragma unroll
  for (int d = 1; d < 1024; d <<= 1) {
    int t = (threadIdx.x >= d) ? sh[threadIdx.x - d] : 0;
    __syncthreads();
    sh[threadIdx.x] += t;
    __syncthreads();
  }
  if (threadIdx.x < nb) bsum[threadIdx.x] = sh[threadIdx.x] - v;
}

__global__ __launch_bounds__(1024) void k_scan3(int* __restrict__ off,
                                                const int* __restrict__ bsum,
                                                int* __restrict__ cursor,
                                                int n, int e) {
  int i = blockIdx.x * 1024 + threadIdx.x;
  if (i < n) {
    int o = off[i] + bsum[blockIdx.x];
    off[i] = o;
    cursor[i] = o;
  }
  if (i == 0) off[n] = e;
}

// XCD-partitioned scatter (r7, kept): group g=blockIdx&7 owns destination rows
// [g*step,(g+1)*step) so each CSR region is written by one XCD -> no
// cross-XCD partial-line writeback amplification.
__global__ __launch_bounds__(256) void k_scatter(const int* __restrict__ rows,
                                                 const int* __restrict__ cols,
                                                 const float* __restrict__ vals,
                                                 int* __restrict__ cursor,
                                                 int2* __restrict__ ev,
                                                 int e, int step) {
  int g = blockIdx.x & 7;
  int k = blockIdx.x >> 3;
  int tid = k * blockDim.x + threadIdx.x;
  int nthr = (gridDim.x >> 3) * blockDim.x;
  int rlo = g * step, rhi = rlo + step;
  for (int i = tid; i < e; i += nthr) {
    int r = rows[i];
    if (r >= rlo && r < rhi) {
      int p = atomicAdd(&cursor[r], 1);
      ev[p] = make_int2(cols[i], __float_as_int(vals[i]));
    }
  }
}

// Feature-chunked SpMM, MLP-restored. Block -> chunk g = blockIdx&7 (XCD
// residue; perf-only). 4 waves/block, each wave = ONE row: lane (e8=lane>>3,
// f=lane&7) loads edge base+e8 (64B coalesced, 8 lanes/edge broadcast) and
// gathers hg[c*8+f] from the 3.2MB L2-resident slab — 8 independent gathers
// per iteration, unconditional clamped loads so unroll-4 pipelines. Tail:
// reduce partial sums across e8 groups with 3 shfl_xor; lanes e8==0 store.
__global__ __launch_bounds__(256) void k_spmm(const int* __restrict__ off,
                                              const int2* __restrict__ ev,
                                              const float* __restrict__ hin,
                                              float* __restrict__ hout,
                                              float* __restrict__ accc,
                                              int n, int first, int last) {
  int wid = threadIdx.x >> 6;
  int lane = threadIdx.x & 63;
  int f = lane & 7;
  int e8 = lane >> 3;
  int g = blockIdx.x & 7;
  int r = (blockIdx.x >> 3) * 4 + wid;
  if (r >= n) return;
  const float* __restrict__ hg = hin + (size_t)g * n * 8;
  int s = off[r], e = off[r + 1];
  float a = 0.f;
  #pragma unroll 4
  for (int base = s; base < e; base += 8) {
    int idx = base + e8;
    int cl = (idx < e) ? idx : s;   // unconditional valid address
    int c; float v;
    ld_edge_nt(&ev[cl], c, v);
    if (idx >= e) v = 0.f;          // zero contribution for OOB lanes
    a = fmaf(v, hg[(size_t)c * 8 + f], a);
  }
  a += __shfl_xor(a, 8, 64);
  a += __shfl_xor(a, 16, 64);
  a += __shfl_xor(a, 32, 64);
  if (e8 == 0) {
    size_t o = (size_t)g * n * 8 + (size_t)r * 8 + f;
    if (!last) __builtin_nontemporal_store(a, &hout[o]);
    if (first) {
      __builtin_nontemporal_store(a, &accc[o]);
    } else {
      float prev = __builtin_nontemporal_load(&accc[o]);
      __builtin_nontemporal_store(prev + a, &accc[o]);
    }
  }
}

// accc (chunk-major) -> d_out rows: [sqrt(max(1+||tail||^2,1e-7)), tail],
// tail = sinh(nrm)/nrm * acc, nrm = max(||acc||, 1e-15)
__global__ __launch_bounds__(256) void k_final(const float* __restrict__ accc,
                                               float* __restrict__ out, int n) {
  int wid = (blockIdx.x * blockDim.x + threadIdx.x) >> 6;
  int lane = threadIdx.x & 63;
  if (wid >= n) return;
  float a = accc[(size_t)(lane >> 3) * n * 8 + (size_t)wid * 8 + (lane & 7)];
  float ss = waveReduceSum(a * a);
  float nrm = fmaxf(sqrtf(ss), 1e-15f);
  float sh = sinhf(nrm) / nrm;
  float tl = sh * a;
  float ss2 = waveReduceSum(tl * tl);
  float first = sqrtf(fmaxf(1.0f + ss2, 1e-7f));
  float* row = out + (size_t)wid * 65;
  row[1 + lane] = tl;
  if (lane == 0) row[0] = first;
}

extern "C" void kernel_launch(void* const* d_in, const int* in_sizes, int n_in,
                              void* d_out, int out_size, void* d_ws, size_t ws_size,
                              hipStream_t stream) {
  const float* x = (const float*)d_in[0];
  const int* rows = (const int*)d_in[1];
  const int* cols = (const int*)d_in[2];
  const float* vals = (const float*)d_in[3];
  float* out = (float*)d_out;
  int n = in_sizes[0] / 65;
  int e = in_sizes[1];

  // workspace layout (~90.4 MB total)
  char* w = (char*)d_ws;
  auto alloc = [&](size_t bytes) {
    void* p = (void*)w;
    w += (bytes + 255) & ~(size_t)255;
    return p;
  };
  int* cnt   = (int*)alloc((size_t)n * 4);           // histogram -> cursor
  int* off   = (int*)alloc(((size_t)n + 1) * 4);     // CSR row offsets
  int* bsum  = (int*)alloc(1024 * 4);                // scan block sums
  int2* ev   = (int2*)alloc((size_t)e * 8);          // packed bucketed edges
  float* h0c = (float*)alloc((size_t)n * 64 * 4);    // chunk-major ping
  float* h1c = (float*)alloc((size_t)n * 64 * 4);    // chunk-major pong
  float* acc = (float*)alloc((size_t)n * 64 * 4);    // chunk-major 3-hop acc

  hipMemsetAsync(cnt, 0, (size_t)n * 4, stream);

  int nwb  = (n + 3) / 4;          // 4 waves (1 row each) per 256-thread block
  int nsb  = (n + 1023) / 1024;    // scan blocks
  int step = (n + 7) / 8;          // rows per XCD partition (scatter)
  int sgrid = ((n + 3) / 4) * 8;   // 4 rows/block x 8 chunks

  k_logmap0<<<nwb, 256, 0, stream>>>(x, h0c, n);
  k_hist<<<2048, 256, 0, stream>>>(rows, cnt, e);
  k_scan1<<<nsb, 1024, 0, stream>>>(cnt, off, bsum, n);
  k_scan2<<<1, 1024, 0, stream>>>(bsum, nsb);
  k_scan3<<<nsb, 1024, 0, stream>>>(off, bsum, cnt, n, e);
  k_scatter<<<2048, 256, 0, stream>>>(rows, cols, vals, cnt, ev, e, step);

  k_spmm<<<sgrid, 256, 0, stream>>>(off, ev, h0c, h1c, acc, n, 1, 0);
  k_spmm<<<sgrid, 256, 0, stream>>>(off, ev, h1c, h0c, acc, n, 0, 0);
  k_spmm<<<sgrid, 256, 0, stream>>>(off, ev, h0c, h1c, acc, n, 0, 1);

  k_final<<<nwb, 256, 0, stream>>>(acc, out, n);
}

// Round 16
// 468.121 us; speedup vs baseline: 2.6245x; 2.6245x over previous
//
#include <hip/hip_runtime.h>
#include <math.h>

// HyperbolicGraphConvolution on MI355X.
// N=100000, D=65 (col 0 identically 0 through GCN hops -> propagate 64), E=1.6M.
// History: r8 row-major h, wave/row, coalesced 256B row gathers, shfl bcast:
//   107us/spmm (2.36TB/s, latency x MLP bound, FETCH 197MB).
// r11/r12/r15 chunked variants: FETCH down to 83MB but MLP/write regressions
//   (189us, 334us). Conclusion: bytes are NOT binding; full-line gathers +
//   in-flight bytes ARE. r16 = r8 structure with 4 edges/iter via float4 row
//   reads (1KB/instr, ~4KB in flight/wave with unroll 4, 4x fewer inner instrs).

__device__ __forceinline__ float waveReduceSum(float v) {
  #pragma unroll
  for (int m = 32; m > 0; m >>= 1) v += __shfl_xor(v, m, 64);
  return v;
}

// logmap0 -> row-major t[n][64]
__global__ __launch_bounds__(256) void k_logmap0(const float* __restrict__ x,
                                                 float* __restrict__ t, int n) {
  int wid = (blockIdx.x * blockDim.x + threadIdx.x) >> 6;
  int lane = threadIdx.x & 63;
  if (wid >= n) return;
  const float* row = x + (size_t)wid * 65;
  float x0 = row[0];
  float y = row[1 + lane];
  float ss = waveReduceSum(y * y);
  float nrm = fmaxf(sqrtf(ss), 1e-15f);
  float theta = fmaxf(x0, 1.0f + 1e-7f);
  t[(size_t)wid * 64 + lane] = acoshf(theta) * (y / nrm);
}

__global__ void k_hist(const int* __restrict__ rows, int* __restrict__ cnt, int e) {
  int i = blockIdx.x * blockDim.x + threadIdx.x;
  int stride = gridDim.x * blockDim.x;
  for (; i < e; i += stride) atomicAdd(&cnt[rows[i]], 1);
}

// ---- 3-phase multi-block exclusive scan over cnt[0..n) ----
__global__ __launch_bounds__(1024) void k_scan1(const int* __restrict__ cnt,
                                                int* __restrict__ off,
                                                int* __restrict__ bsum, int n) {
  __shared__ int sh[1024];
  int i = blockIdx.x * 1024 + threadIdx.x;
  int v = (i < n) ? cnt[i] : 0;
  sh[threadIdx.x] = v;
  __syncthreads();
  #pragma unroll
  for (int d = 1; d < 1024; d <<= 1) {
    int t = (threadIdx.x >= d) ? sh[threadIdx.x - d] : 0;
    __syncthreads();
    sh[threadIdx.x] += t;
    __syncthreads();
  }
  if (i < n) off[i] = sh[threadIdx.x] - v;
  if (threadIdx.x == 1023) bsum[blockIdx.x] = sh[1023];
}

__global__ __launch_bounds__(1024) void k_scan2(int* __restrict__ bsum, int nb) {
  __shared__ int sh[1024];
  int v = (threadIdx.x < nb) ? bsum[threadIdx.x] : 0;
  sh[threadIdx.x] = v;
  __syncthreads();
  #pragma unroll
  for (int d = 1; d < 1024; d <<= 1) {
    int t = (threadIdx.x >= d) ? sh[threadIdx.x - d] : 0;
    __syncthreads();
    sh[threadIdx.x] += t;
    __syncthreads();
  }
  if (threadIdx.x < nb) bsum[threadIdx.x] = sh[threadIdx.x] - v;
}

__global__ __launch_bounds__(1024) void k_scan3(int* __restrict__ off,
                                                const int* __restrict__ bsum,
                                                int* __restrict__ cursor,
                                                int n, int e) {
  int i = blockIdx.x * 1024 + threadIdx.x;
  if (i < n) {
    int o = off[i] + bsum[blockIdx.x];
    off[i] = o;
    cursor[i] = o;
  }
  if (i == 0) off[n] = e;
}

// XCD-partitioned scatter (r7): group g=blockIdx&7 owns destination rows
// [g*step,(g+1)*step) -> each CSR region written by one XCD, no cross-XCD
// partial-line writeback amplification.
__global__ __launch_bounds__(256) void k_scatter(const int* __restrict__ rows,
                                                 const int* __restrict__ cols,
                                                 const float* __restrict__ vals,
                                                 int* __restrict__ cursor,
                                                 int2* __restrict__ ev,
                                                 int e, int step) {
  int g = blockIdx.x & 7;
  int k = blockIdx.x >> 3;
  int tid = k * blockDim.x + threadIdx.x;
  int nthr = (gridDim.x >> 3) * blockDim.x;
  int rlo = g * step, rhi = rlo + step;
  for (int i = tid; i < e; i += nthr) {
    int r = rows[i];
    if (r >= rlo && r < rhi) {
      int p = atomicAdd(&cursor[r], 1);
      ev[p] = make_int2(cols[i], __float_as_int(vals[i]));
    }
  }
}

// SpMM, one wave per row, 4-edges-per-iteration float4 gathers.
// Lane = (j4 = lane>>4, q = lane&15). Batch: 64 packed edges loaded coalesced
// (8B/lane, OOB lanes v=0). Inner iter t: group j4 gets edge 4t+j4 via shfl,
// 16 lanes read that row's floats [q*4 .. q*4+3] -> one dwordx4/lane, 1KB и
// 4 independent 256B rows per instruction; unroll 4 => ~4KB in flight/wave.
// Reduce across j4 groups (8 shfl_xor), lanes<16 store float4 (aligned).
__global__ __launch_bounds__(256) void k_spmm(const int* __restrict__ off,
                                              const int2* __restrict__ ev,
                                              const float* __restrict__ hin,
                                              float* __restrict__ hout,
                                              float* __restrict__ acc,
                                              int n, int first, int last) {
  int wid = (blockIdx.x * blockDim.x + threadIdx.x) >> 6;
  int lane = threadIdx.x & 63;
  if (wid >= n) return;
  int q = lane & 15;
  int j4 = lane >> 4;
  int s = off[wid], e = off[wid + 1];
  float4 a = make_float4(0.f, 0.f, 0.f, 0.f);
  for (int base = s; base < e; base += 64) {
    int idx = base + lane;
    int2 cv = (idx < e) ? ev[idx] : make_int2(0, 0);
    int m = min(64, e - base);
    int nt4 = (m + 3) >> 2;
    #pragma unroll 4
    for (int t = 0; t < nt4; ++t) {
      int src = 4 * t + j4;
      int cj = __shfl(cv.x, src, 64);
      float vj = __int_as_float(__shfl(cv.y, src, 64));
      const float4 hr =
          *reinterpret_cast<const float4*>(&hin[(size_t)cj * 64 + q * 4]);
      a.x = fmaf(vj, hr.x, a.x);
      a.y = fmaf(vj, hr.y, a.y);
      a.z = fmaf(vj, hr.z, a.z);
      a.w = fmaf(vj, hr.w, a.w);
    }
  }
  // reduce the 4 j4-groups onto j4==0 lanes
  #pragma unroll
  for (int m4 = 16; m4 <= 32; m4 <<= 1) {
    a.x += __shfl_xor(a.x, m4, 64);
    a.y += __shfl_xor(a.y, m4, 64);
    a.z += __shfl_xor(a.z, m4, 64);
    a.w += __shfl_xor(a.w, m4, 64);
  }
  if (j4 == 0) {
    size_t o = (size_t)wid * 64 + q * 4;
    if (!last) *reinterpret_cast<float4*>(&hout[o]) = a;
    if (first) {
      *reinterpret_cast<float4*>(&acc[o]) = a;
    } else {
      float4 p = *reinterpret_cast<const float4*>(&acc[o]);
      p.x += a.x; p.y += a.y; p.z += a.z; p.w += a.w;
      *reinterpret_cast<float4*>(&acc[o]) = p;
    }
  }
}

// acc[n][64] -> d_out rows: [sqrt(max(1+||tail||^2,1e-7)), tail],
// tail = sinh(nrm)/nrm * acc, nrm = max(||acc||, 1e-15)
__global__ __launch_bounds__(256) void k_final(const float* __restrict__ acc,
                                               float* __restrict__ out, int n) {
  int wid = (blockIdx.x * blockDim.x + threadIdx.x) >> 6;
  int lane = threadIdx.x & 63;
  if (wid >= n) return;
  float a = acc[(size_t)wid * 64 + lane];
  float ss = waveReduceSum(a * a);
  float nrm = fmaxf(sqrtf(ss), 1e-15f);
  float sh = sinhf(nrm) / nrm;
  float tl = sh * a;
  float ss2 = waveReduceSum(tl * tl);
  float first = sqrtf(fmaxf(1.0f + ss2, 1e-7f));
  float* row = out + (size_t)wid * 65;
  row[1 + lane] = tl;
  if (lane == 0) row[0] = first;
}

extern "C" void kernel_launch(void* const* d_in, const int* in_sizes, int n_in,
                              void* d_out, int out_size, void* d_ws, size_t ws_size,
                              hipStream_t stream) {
  const float* x = (const float*)d_in[0];
  const int* rows = (const int*)d_in[1];
  const int* cols = (const int*)d_in[2];
  const float* vals = (const float*)d_in[3];
  float* out = (float*)d_out;
  int n = in_sizes[0] / 65;
  int e = in_sizes[1];

  // workspace layout (~90 MB total)
  char* w = (char*)d_ws;
  auto alloc = [&](size_t bytes) {
    void* p = (void*)w;
    w += (bytes + 255) & ~(size_t)255;
    return p;
  };
  int* cnt   = (int*)alloc((size_t)n * 4);           // histogram -> cursor
  int* off   = (int*)alloc(((size_t)n + 1) * 4);     // CSR row offsets
  int* bsum  = (int*)alloc(1024 * 4);                // scan block sums
  int2* ev   = (int2*)alloc((size_t)e * 8);          // packed bucketed edges
  float* h0  = (float*)alloc((size_t)n * 64 * 4);    // row-major ping
  float* h1  = (float*)alloc((size_t)n * 64 * 4);    // row-major pong
  float* acc = (float*)alloc((size_t)n * 64 * 4);    // row-major 3-hop acc

  hipMemsetAsync(cnt, 0, (size_t)n * 4, stream);

  int nwb  = (n + 3) / 4;          // 4 waves (1 row each) per 256-thread block
  int nsb  = (n + 1023) / 1024;    // scan blocks
  int step = (n + 7) / 8;          // rows per XCD partition (scatter)

  k_logmap0<<<nwb, 256, 0, stream>>>(x, h0, n);
  k_hist<<<2048, 256, 0, stream>>>(rows, cnt, e);
  k_scan1<<<nsb, 1024, 0, stream>>>(cnt, off, bsum, n);
  k_scan2<<<1, 1024, 0, stream>>>(bsum, nsb);
  k_scan3<<<nsb, 1024, 0, stream>>>(off, bsum, cnt, n, e);
  k_scatter<<<2048, 256, 0, stream>>>(rows, cols, vals, cnt, ev, e, step);

  k_spmm<<<nwb, 256, 0, stream>>>(off, ev, h0, h1, acc, n, 1, 0);
  k_spmm<<<nwb, 256, 0, stream>>>(off, ev, h1, h0, acc, n, 0, 0);
  k_spmm<<<nwb, 256, 0, stream>>>(off, ev, h0, h1, acc, n, 0, 1);

  k_final<<<nwb, 256, 0, stream>>>(acc, out, n);
}